// Round 16
// baseline (877.102 us; speedup 1.0000x reference)
//
#include <hip/hip_runtime.h>
#include <hip/hip_bf16.h>
#include <math.h>

// Problem constants
#define NB   2
#define NT   4096
#define ND   2048
#define NH   16
#define NDK  128
#define NCL  512
#define NNC  8
#define NTOK 8192
#define SCALING 0.08838834764831845f  // 128^-0.5

typedef unsigned short u16;
typedef short short8 __attribute__((ext_vector_type(8)));
typedef unsigned short ushort8 __attribute__((ext_vector_type(8)));
typedef float f32x4 __attribute__((ext_vector_type(4)));
typedef float float4v __attribute__((ext_vector_type(4)));
typedef short short4v __attribute__((ext_vector_type(4)));

__device__ __forceinline__ float bf2f(u16 u) {
    union { unsigned int i; float f; } v; v.i = ((unsigned int)u) << 16; return v.f;
}
__device__ __forceinline__ u16 f2bf(float f) {
    union { float f; unsigned int i; } v; v.f = f;
    unsigned int r = v.i + 0x7FFFu + ((v.i >> 16) & 1u);
    return (u16)(r >> 16);
}

// async global->LDS, 16B per lane. LDS dest linear: wave base + lane*16.
__device__ __forceinline__ void gload16(const void* g, void* l) {
    __builtin_amdgcn_global_load_lds(
        (const __attribute__((address_space(1))) unsigned int*)g,
        (__attribute__((address_space(3))) unsigned int*)l, 16, 0, 0);
}

#define MFMA16(acc_, a_, b_) acc_ = __builtin_amdgcn_mfma_f32_16x16x32_bf16(a_, b_, acc_, 0, 0, 0)
#define SBAR  asm volatile("s_barrier" ::: "memory")

// ===========================================================================
// ROUND-8 GEMM core: 256x256 tile, barrier-minimal (1 sync per K-tile),
// global_load_lds into the non-read buffer pair.
// ===========================================================================

// stage one 128x64 half-tile
__device__ __forceinline__ void stage_half(const u16* __restrict__ g, int ld,
                                           u16* lds, int tid)
{
#pragma unroll
    for (int j = 0; j < 2; ++j) {
        int c = tid + j * 512;            // 0..1023 16B chunks
        int row = c >> 3, u = c & 7;
        gload16(g + (size_t)row * ld + ((u ^ (row & 7)) * 8), lds + (size_t)c * 8);
    }
}

__device__ __forceinline__ void tile_nb(
    int G, int nkt,
    const u16* Aop, const u16* Bop, int ld,
    int tid, int arow, int brow, int uc0, int uc1,
    u16* ARd, u16* BRd, u16* AWr, u16* BWr,
    f32x4 acc[8][4])
{
    if (G + 1 < nkt) {
        const u16* Ag = Aop + (size_t)(G + 1) * 64;
        const u16* Bg = Bop + (size_t)(G + 1) * 64;
        stage_half(Ag,                    ld, AWr,        tid);
        stage_half(Ag + (size_t)128 * ld, ld, AWr + 8192, tid);
        stage_half(Bg,                    ld, BWr,        tid);
        stage_half(Bg + (size_t)128 * ld, ld, BWr + 8192, tid);
    }

    short8 a[4][2], bA[2][2], bB[2][2];

    // group 0: (m0, n0)
#pragma unroll
    for (int mf = 0; mf < 4; ++mf) {
        a[mf][0] = *(const short8*)(ARd + (size_t)(arow + mf * 16) * 64 + uc0);
        a[mf][1] = *(const short8*)(ARd + (size_t)(arow + mf * 16) * 64 + uc1);
    }
#pragma unroll
    for (int nf = 0; nf < 2; ++nf) {
        bA[nf][0] = *(const short8*)(BRd + (size_t)(brow + nf * 16) * 64 + uc0);
        bA[nf][1] = *(const short8*)(BRd + (size_t)(brow + nf * 16) * 64 + uc1);
    }
    __builtin_amdgcn_s_setprio(1);
#pragma unroll
    for (int mf = 0; mf < 4; ++mf)
#pragma unroll
        for (int nf = 0; nf < 2; ++nf) {
            MFMA16(acc[mf][nf], a[mf][0], bA[nf][0]);
            MFMA16(acc[mf][nf], a[mf][1], bA[nf][1]);
        }
    __builtin_amdgcn_s_setprio(0);

    // group 1: (m0, n1)
#pragma unroll
    for (int nf = 0; nf < 2; ++nf) {
        bB[nf][0] = *(const short8*)(BRd + (size_t)(brow + 32 + nf * 16) * 64 + uc0);
        bB[nf][1] = *(const short8*)(BRd + (size_t)(brow + 32 + nf * 16) * 64 + uc1);
    }
    __builtin_amdgcn_s_setprio(1);
#pragma unroll
    for (int mf = 0; mf < 4; ++mf)
#pragma unroll
        for (int nf = 0; nf < 2; ++nf) {
            MFMA16(acc[mf][2 + nf], a[mf][0], bB[nf][0]);
            MFMA16(acc[mf][2 + nf], a[mf][1], bB[nf][1]);
        }
    __builtin_amdgcn_s_setprio(0);

    // group 2: (m1, n1)
#pragma unroll
    for (int mf = 0; mf < 4; ++mf) {
        a[mf][0] = *(const short8*)(ARd + (size_t)(arow + 64 + mf * 16) * 64 + uc0);
        a[mf][1] = *(const short8*)(ARd + (size_t)(arow + 64 + mf * 16) * 64 + uc1);
    }
    __builtin_amdgcn_s_setprio(1);
#pragma unroll
    for (int mf = 0; mf < 4; ++mf)
#pragma unroll
        for (int nf = 0; nf < 2; ++nf) {
            MFMA16(acc[4 + mf][2 + nf], a[mf][0], bB[nf][0]);
            MFMA16(acc[4 + mf][2 + nf], a[mf][1], bB[nf][1]);
        }
    __builtin_amdgcn_s_setprio(0);

    // group 3: (m1, n0)
    __builtin_amdgcn_s_setprio(1);
#pragma unroll
    for (int mf = 0; mf < 4; ++mf)
#pragma unroll
        for (int nf = 0; nf < 2; ++nf) {
            MFMA16(acc[4 + mf][nf], a[mf][0], bA[nf][0]);
            MFMA16(acc[4 + mf][nf], a[mf][1], bA[nf][1]);
        }
    __builtin_amdgcn_s_setprio(0);

    asm volatile("s_waitcnt vmcnt(0) lgkmcnt(0)" ::: "memory");
    SBAR;
}

__device__ __forceinline__ void gemm256_core(
    const u16* Aop, const u16* Bop,
    int ld, int nkt,
    u16* A0, u16* A1, u16* B0, u16* B1, f32x4 acc[8][4])
{
    const int tid  = threadIdx.x;
    const int lane = tid & 63;
    const int lr   = lane & 15;
    const int lg   = lane >> 4;
    const int wid  = tid >> 6;
    const int wm   = wid >> 2;
    const int wn   = wid & 3;

    const int swz  = lr & 7;
    const int uc0  = ((0 * 4 + lg) ^ swz) * 8;
    const int uc1  = ((1 * 4 + lg) ^ swz) * 8;
    const int arow = wm * 128 + lr;
    const int brow = wn * 64 + lr;

    stage_half(Aop,                    ld, A0,        tid);
    stage_half(Aop + (size_t)128 * ld, ld, A0 + 8192, tid);
    stage_half(Bop,                    ld, B0,        tid);
    stage_half(Bop + (size_t)128 * ld, ld, B0 + 8192, tid);
    asm volatile("s_waitcnt vmcnt(0)" ::: "memory");
    SBAR;

    for (int G = 0; G < nkt; G += 2) {
        tile_nb(G,     nkt, Aop, Bop, ld, tid, arow, brow, uc0, uc1,
                A0, B0, A1, B1, acc);
        tile_nb(G + 1, nkt, Aop, Bop, ld, tid, arow, brow, uc0, uc1,
                A1, B1, A0, B0, acc);
    }
}

// ---------------------------------------------------------------------------
// Old 128x128 core (kept for the small GEMMs: kv, combine)
// ---------------------------------------------------------------------------
__device__ __forceinline__ void gemm_bt_core(
    const u16* __restrict__ A, const u16* __restrict__ Bm,
    int lda, int ldb, int K, u16* As, u16* Bs, f32x4 acc[4][4])
{
    const int tid  = threadIdx.x;
    const int lane = tid & 63;
    const int lr   = lane & 15;
    const int lg   = lane >> 4;
    const int wid  = tid >> 6;
    const int wr   = (wid >> 1) * 64;
    const int wc   = (wid & 1) * 64;
    for (int kt = 0; kt < K; kt += 64) {
#pragma unroll
        for (int i = 0; i < 4; ++i) {
            int c = tid + i * 256;
            int row = c >> 3, col = (c & 7) * 8;
            gload16(A  + (size_t)row * lda + kt + col, (char*)As + (size_t)c * 16);
            gload16(Bm + (size_t)row * ldb + kt + col, (char*)Bs + (size_t)c * 16);
        }
        __syncthreads();
#pragma unroll
        for (int kk = 0; kk < 2; ++kk) {
            short8 a[4], b[4];
#pragma unroll
            for (int m = 0; m < 4; ++m)
                a[m] = *(const short8*)(As + (wr + m * 16 + lr) * 64 + kk * 32 + lg * 8);
#pragma unroll
            for (int n = 0; n < 4; ++n)
                b[n] = *(const short8*)(Bs + (wc + n * 16 + lr) * 64 + kk * 32 + lg * 8);
#pragma unroll
            for (int m = 0; m < 4; ++m)
#pragma unroll
                for (int n = 0; n < 4; ++n)
                    acc[m][n] = __builtin_amdgcn_mfma_f32_16x16x32_bf16(a[m], b[n], acc[m][n], 0, 0, 0);
        }
        __syncthreads();
    }
}

// ---------------------------------------------------------------------------
// Merged fp32 -> bf16 convert for all six tensors (one launch).
// ---------------------------------------------------------------------------
__global__ __launch_bounds__(256) void k_f2bf_all(
    const float* __restrict__ sx,  u16* __restrict__ dx,
    const float* __restrict__ s1,  u16* __restrict__ d1,
    const float* __restrict__ s2,  u16* __restrict__ d2,
    const float* __restrict__ s3,  u16* __restrict__ d3,
    const float* __restrict__ s4,  u16* __restrict__ d4,
    const float* __restrict__ s5,  u16* __restrict__ d5)
{
    const float* src;
    u16* dst;
    int n4, base = blockIdx.x;
    if (base < 2048)      { src = sx; dst = dx; n4 = 4194304; }
    else if (base < 3072) { src = s1; dst = d1; n4 = 1048576; base -= 2048; }
    else if (base < 4096) { src = s2; dst = d2; n4 = 1048576; base -= 3072; }
    else if (base < 5120) { src = s3; dst = d3; n4 = 1048576; base -= 4096; }
    else if (base < 6144) { src = s4; dst = d4; n4 = 1048576; base -= 5120; }
    else                  { src = s5; dst = d5; n4 = 1048576; base -= 6144; }
    int nblk = (blockIdx.x < 2048) ? 2048 : 1024;
    int i = base * blockDim.x + threadIdx.x;
    int stride = nblk * blockDim.x;
    for (int j = i; j < n4; j += stride) {
        float4v f = *(const float4v*)(src + (size_t)j * 4);
        short4v o;
        o.x = (short)f2bf(f.x); o.y = (short)f2bf(f.y);
        o.z = (short)f2bf(f.z); o.w = (short)f2bf(f.w);
        *(short4v*)(dst + (size_t)j * 4) = o;
    }
}

// ---------------------------------------------------------------------------
// GEMM1: [8192 x 2048] x [8192 x 2048]^T; fused epilogue.
// XCD chunking: 16mt x 8nt 2-D blocks per XCD (24-panel footprint vs 36).
// ---------------------------------------------------------------------------
__global__ __launch_bounds__(512, 2) void k_gemm1(
    const u16* __restrict__ xb, const u16* __restrict__ wb,
    const float* __restrict__ bq, const float* __restrict__ bk,
    const float* __restrict__ bv, const float* __restrict__ bg,
    const float* __restrict__ sinp, const float* __restrict__ cosp,
    const float* __restrict__ maskp,
    u16* __restrict__ qro, u16* __restrict__ kro, u16* __restrict__ krwT,
    u16* __restrict__ vT, u16* __restrict__ glin)
{
    __shared__ __align__(16) u16 A0[256 * 64];
    __shared__ __align__(16) u16 A1[256 * 64];
    __shared__ __align__(16) u16 B0[256 * 64];
    __shared__ __align__(16) u16 B1[256 * 64];
    f32x4 acc[8][4];
#pragma unroll
    for (int m = 0; m < 8; ++m)
#pragma unroll
        for (int n = 0; n < 4; ++n) acc[m][n] = (f32x4){0.f, 0.f, 0.f, 0.f};

    // bijective 2-D blocked XCD swizzle: chunk c (= XCD) covers 16mt x 8nt
    int bid = blockIdx.x;
    int c = bid & 7, i = bid >> 3;           // c: XCD chunk, i: 0..127
    int cm = c >> 2, cn = c & 3;             // 2 x 4 chunk grid
    int mt = cm * 16 + (i & 15);             // 0..31
    int nt = cn * 8 + (i >> 4);              // 0..31

    gemm256_core(xb + (size_t)mt * 256 * ND, wb + (size_t)nt * 256 * ND,
                 ND, ND / 64, A0, A1, B0, B1, acc);

    int tid = threadIdx.x, lane = tid & 63, lr = lane & 15, lg = lane >> 4, wid = tid >> 6;
    int wm = wid >> 2, wn = wid & 3;
    int which = nt >> 3;

    if (which <= 1) {
        const float* bias = (which == 0) ? bq : bk;
#pragma unroll
        for (int mf = 0; mf < 8; ++mf) {
#pragma unroll
            for (int nf = 0; nf < 4; ++nf) {
#pragma unroll
                for (int r = 0; r < 4; ++r) {
                    int row = mt * 256 + wm * 128 + mf * 16 + lg * 4 + r;
                    int col = nt * 256 + wn * 64 + nf * 16 + lr;
                    int f = col & 2047, h = f >> 7, d = f & 127;
                    int b = row >> 12, t = row & 4095, cnn = t >> 9, cl = t & 511;
                    float v = acc[mf][nf][r] + bias[f];
                    if (which == 1) v *= SCALING;
                    float sv = sinp[(size_t)t * NDK + d];
                    float cv = cosp[(size_t)t * NDK + d];
                    float vp = __shfl_xor(v, 1);
                    float rot = (lr & 1) ? vp : -vp;
                    float o = v * cv + rot * sv;
                    size_t chbase = (size_t)(b * NNC + cnn) * NH + h;
                    if (which == 0) {
                        qro[(chbase * NCL + cl) * NDK + d] = f2bf(o);
                    } else {
                        kro[(chbase * NCL + cl) * NDK + d] = f2bf(o);
                        float w = maskp[((size_t)h * NCL + (NCL - 1)) * NCL + cl];
                        krwT[(chbase * NDK + d) * NCL + cl] = f2bf(o * w);
                    }
                }
            }
        }
    } else {
#pragma unroll
        for (int mf = 0; mf < 8; ++mf) {
#pragma unroll
            for (int nf = 0; nf < 4; ++nf) {
#pragma unroll
                for (int r = 0; r < 4; ++r) {
                    int row = mt * 256 + wm * 128 + mf * 16 + lg * 4 + r;
                    int col = nt * 256 + wn * 64 + nf * 16 + lr;
                    int f = col & 2047;
                    float v = acc[mf][nf][r];
                    if (which == 2) {
                        int h = f >> 7, d = f & 127;
                        int b = row >> 12, t = row & 4095, cnn = t >> 9, cl = t & 511;
                        vT[(((size_t)(b * NNC + cnn) * NH + h) * NDK + d) * NCL + cl] = f2bf(v + bv[f]);
                    } else {
                        glin[(size_t)row * ND + f] = f2bf(v + bg[f]);
                    }
                }
            }
        }
    }
}

// ---------------------------------------------------------------------------
// GEMM2: y[8192x2048] x wo[2048x2048]^T + bo -> fp32 out
// XCD chunking: 8mt x 4nt 2-D blocks per XCD.
// ---------------------------------------------------------------------------
__global__ __launch_bounds__(512, 2) void k_gemm2(
    const u16* __restrict__ y, const u16* __restrict__ wob,
    const float* __restrict__ bo, float* __restrict__ out)
{
    __shared__ __align__(16) u16 A0[256 * 64];
    __shared__ __align__(16) u16 A1[256 * 64];
    __shared__ __align__(16) u16 B0[256 * 64];
    __shared__ __align__(16) u16 B1[256 * 64];
    f32x4 acc[8][4];
#pragma unroll
    for (int m = 0; m < 8; ++m)
#pragma unroll
        for (int n = 0; n < 4; ++n) acc[m][n] = (f32x4){0.f, 0.f, 0.f, 0.f};

    // bijective 2-D blocked XCD swizzle: grid 32mt x 8nt; chunk = 8mt x 4nt
    int bid = blockIdx.x;
    int c = bid & 7, i = bid >> 3;           // i: 0..31
    int cm = c >> 1, cn = c & 1;             // 4 x 2 chunk grid
    int mt = cm * 8 + (i & 7);               // 0..31
    int nt = cn * 4 + (i >> 3);              // 0..7

    gemm256_core(y + (size_t)mt * 256 * ND, wob + (size_t)nt * 256 * ND,
                 ND, ND / 64, A0, A1, B0, B1, acc);

    int tid = threadIdx.x, lane = tid & 63, lr = lane & 15, lg = lane >> 4, wid = tid >> 6;
    int wm = wid >> 2, wn = wid & 3;
#pragma unroll
    for (int mf = 0; mf < 8; ++mf)
#pragma unroll
        for (int nf = 0; nf < 4; ++nf)
#pragma unroll
            for (int r = 0; r < 4; ++r) {
                int row = mt * 256 + wm * 128 + mf * 16 + lg * 4 + r;
                int col = nt * 256 + wn * 64 + nf * 16 + lr;
                out[(size_t)row * ND + col] = acc[mf][nf][r] + bo[col];
            }
}

// ---------------------------------------------------------------------------
// Inner retention, KVBLK=64, Q direct-to-reg; iraw stored BF16.
// ---------------------------------------------------------------------------
__global__ __launch_bounds__(256) void k_inner(
    const u16* __restrict__ qr, const u16* __restrict__ kr,
    const u16* __restrict__ vT, const float* __restrict__ mask,
    u16* __restrict__ iraw, float* __restrict__ iscale)
{
    __shared__ __align__(16) u16 Ks[64 * 128];
    __shared__ __align__(16) u16 Vs[128 * 64];
    __shared__ __align__(16) u16 Ps[4][32 * 64];
    __shared__ float sl[128];

    int qt = blockIdx.x, bnh = blockIdx.y;
    int h = bnh & 15;
    const u16* Q = qr + (size_t)bnh * NCL * NDK + (size_t)qt * 128 * NDK;
    const u16* K = kr + (size_t)bnh * NCL * NDK;
    const u16* V = vT + (size_t)bnh * NDK * NCL;
    const float* M = mask + (size_t)h * NCL * NCL + (size_t)qt * 128 * NCL;

    int tid = threadIdx.x, lane = tid & 63, lr = lane & 15, lg = lane >> 4, wid = tid >> 6;
    if (tid < 128) sl[tid] = 0.f;

    short8 aq[2][4];
#pragma unroll
    for (int i = 0; i < 2; ++i)
#pragma unroll
        for (int kk = 0; kk < 4; ++kk)
            aq[i][kk] = *(const short8*)(Q + (size_t)(wid * 32 + i * 16 + lr) * NDK + kk * 32 + lg * 8);

    f32x4 acc[2][8];
#pragma unroll
    for (int i = 0; i < 2; ++i)
#pragma unroll
        for (int n = 0; n < 8; ++n) acc[i][n] = (f32x4){0.f, 0.f, 0.f, 0.f};

    int msteps = qt * 2 + 2;
    for (int ms = 0; ms < msteps; ++ms) {
        int mb = ms * 64;
#pragma unroll
        for (int i = 0; i < 4; ++i) {
            int c = tid + i * 256;
            int row = c >> 4, cc = (c & 15) * 8;
            gload16(K + (size_t)(mb + row) * NDK + cc, (char*)Ks + (size_t)c * 16);
        }
#pragma unroll
        for (int i = 0; i < 4; ++i) {
            int c = tid + i * 256;
            int row = c >> 3, cc = (c & 7) * 8;
            gload16(V + (size_t)row * NCL + mb + cc, (char*)Vs + (size_t)c * 16);
        }
        __syncthreads();

        f32x4 pa[2][4];
#pragma unroll
        for (int i = 0; i < 2; ++i)
#pragma unroll
            for (int nf = 0; nf < 4; ++nf) pa[i][nf] = (f32x4){0.f, 0.f, 0.f, 0.f};
#pragma unroll
        for (int kk = 0; kk < 4; ++kk) {
#pragma unroll
            for (int nf = 0; nf < 4; ++nf) {
                short8 bk = *(const short8*)(Ks + (size_t)(nf * 16 + lr) * 128 + kk * 32 + lg * 8);
#pragma unroll
                for (int i = 0; i < 2; ++i)
                    pa[i][nf] = __builtin_amdgcn_mfma_f32_16x16x32_bf16(aq[i][kk], bk, pa[i][nf], 0, 0, 0);
            }
        }
#pragma unroll
        for (int i = 0; i < 2; ++i) {
#pragma unroll
            for (int r = 0; r < 4; ++r) {
                int rloc = i * 16 + lg * 4 + r;
                int row128 = wid * 32 + rloc;
                float ss = 0.f;
#pragma unroll
                for (int nf = 0; nf < 4; ++nf) {
                    float mv = M[(size_t)row128 * NCL + mb + nf * 16 + lr];
                    float p = pa[i][nf][r] * mv;
                    ss += fabsf(p);
                    Ps[wid][rloc * 64 + nf * 16 + lr] = f2bf(p);
                }
                ss += __shfl_xor(ss, 1); ss += __shfl_xor(ss, 2);
                ss += __shfl_xor(ss, 4); ss += __shfl_xor(ss, 8);
                if (lr == 0) sl[row128] += ss;
            }
        }
        __syncthreads();

        short8 ap[2][2];
#pragma unroll
        for (int i = 0; i < 2; ++i)
#pragma unroll
            for (int ks = 0; ks < 2; ++ks)
                ap[i][ks] = *(const short8*)(Ps[wid] + (i * 16 + lr) * 64 + ks * 32 + lg * 8);
#pragma unroll
        for (int n = 0; n < 8; ++n) {
#pragma unroll
            for (int ks = 0; ks < 2; ++ks) {
                short8 bv8 = *(const short8*)(Vs + (size_t)(n * 16 + lr) * 64 + ks * 32 + lg * 8);
#pragma unroll
                for (int i = 0; i < 2; ++i)
                    acc[i][n] = __builtin_amdgcn_mfma_f32_16x16x32_bf16(ap[i][ks], bv8, acc[i][n], 0, 0, 0);
            }
        }
        __syncthreads();
    }

    u16* OR = iraw + ((size_t)bnh * NCL + (size_t)qt * 128) * NDK;
#pragma unroll
    for (int i = 0; i < 2; ++i)
#pragma unroll
        for (int n = 0; n < 8; ++n)
#pragma unroll
            for (int r = 0; r < 4; ++r) {
                int row = wid * 32 + i * 16 + lg * 4 + r;
                int col = n * 16 + lr;
                OR[(size_t)row * NDK + col] = f2bf(acc[i][n][r]);
            }
    if (tid < 128) iscale[(size_t)bnh * NCL + qt * 128 + tid] = fmaxf(1.f, sl[tid]);
}

// ---------------------------------------------------------------------------
// kv_i[k][d] = sum_l krw[l][k] * v[l][d]
// ---------------------------------------------------------------------------
__global__ __launch_bounds__(256) void k_kv(
    const u16* __restrict__ krwT, const u16* __restrict__ vT, float* __restrict__ kvi)
{
    __shared__ __align__(16) u16 As[128 * 64];
    __shared__ __align__(16) u16 Bs[128 * 64];
    f32x4 acc[4][4];
#pragma unroll
    for (int m = 0; m < 4; ++m)
#pragma unroll
        for (int n = 0; n < 4; ++n) acc[m][n] = (f32x4){0.f, 0.f, 0.f, 0.f};

    int bnh = blockIdx.x;
    gemm_bt_core(krwT + (size_t)bnh * NDK * NCL, vT + (size_t)bnh * NDK * NCL,
                 NCL, NCL, NCL, As, Bs, acc);

    int tid = threadIdx.x, lane = tid & 63, lr = lane & 15, lg = lane >> 4, wid = tid >> 6;
    int wr = (wid >> 1) * 64, wc = (wid & 1) * 64;
    float* O = kvi + (size_t)bnh * NDK * NDK;
#pragma unroll
    for (int m = 0; m < 4; ++m)
#pragma unroll
        for (int n = 0; n < 4; ++n)
#pragma unroll
            for (int r = 0; r < 4; ++r) {
                int row = wr + m * 16 + lg * 4 + r;
                int col = wc + n * 16 + lr;
                O[(size_t)row * NDK + col] = acc[m][n][r];
            }
}

// ---------------------------------------------------------------------------
// Recurrent scan over chunks
// ---------------------------------------------------------------------------
__global__ __launch_bounds__(256) void k_scan(
    const float* __restrict__ kvi, const float* __restrict__ cdec,
    u16* __restrict__ kvrT, float* __restrict__ csc)
{
    int bh = blockIdx.x;
    int b = bh >> 4, h = bh & 15;
    float cd = cdec[h];
    int tid = threadIdx.x;
    int col = tid & 127;
    int r0 = (tid >> 7) * 64;
    float st[64];
#pragma unroll
    for (int i = 0; i < 64; ++i) st[i] = 0.f;
    float scale = 1.f;
    __shared__ float cs[128];
    __shared__ float scsh;

    for (int n = 0; n < NNC; ++n) {
        size_t idx = (size_t)((b * NNC + n) * NH + h);
        size_t kb = idx * (NDK * NDK);
        float inv = 1.f / scale;
#pragma unroll
        for (int i = 0; i < 64; ++i)
            kvrT[kb + (size_t)col * NDK + r0 + i] = f2bf(st[i] * inv);
        if (tid == 0) csc[idx] = scale;

        const float* KV = kvi + kb;
        float colsum = 0.f;
#pragma unroll
        for (int i = 0; i < 64; ++i) {
            float xv = st[i] * cd + KV[(size_t)(r0 + i) * NDK + col];
            st[i] = xv;
            colsum += fabsf(xv);
        }
        __syncthreads();
        if (tid < 128) cs[tid] = 0.f;
        __syncthreads();
        atomicAdd(&cs[col], colsum);
        __syncthreads();
        if (tid == 0) {
            float mx = cs[0];
            for (int i = 1; i < 128; ++i) mx = fmaxf(mx, cs[i]);
            scsh = fmaxf(1.f, mx);
        }
        __syncthreads();
        scale = scsh;
    }
}

// ---------------------------------------------------------------------------
// Combine (iraw read as BF16)
// ---------------------------------------------------------------------------
__global__ __launch_bounds__(256) void k_combine(
    const u16* __restrict__ qr, const u16* __restrict__ kvrT,
    const u16* __restrict__ iraw, const float* __restrict__ iscale,
    const float* __restrict__ cscale, const float* __restrict__ idecay,
    const u16* __restrict__ glin, u16* __restrict__ y)
{
    __shared__ __align__(16) u16 As[128 * 64];
    __shared__ __align__(16) u16 Bs[128 * 64];
    __shared__ float ssum[128];
    __shared__ float ssq[128];
    f32x4 acc[4][4];
#pragma unroll
    for (int m = 0; m < 4; ++m)
#pragma unroll
        for (int n = 0; n < 4; ++n) acc[m][n] = (f32x4){0.f, 0.f, 0.f, 0.f};

    int qt = blockIdx.x, bnh = blockIdx.y;
    int b = bnh >> 7, cn = (bnh >> 4) & 7, h = bnh & 15;
    gemm_bt_core(qr + (size_t)bnh * NCL * NDK + (size_t)qt * 128 * NDK,
                 kvrT + (size_t)bnh * NDK * NDK, NDK, NDK, NDK, As, Bs, acc);

    int tid = threadIdx.x, lane = tid & 63, lr = lane & 15, lg = lane >> 4, wid = tid >> 6;
    int wr = (wid >> 1) * 64, wc = (wid & 1) * 64;
    if (tid < 128) { ssum[tid] = 0.f; ssq[tid] = 0.f; }
    __syncthreads();
    float csv = cscale[bnh];

#pragma unroll
    for (int m = 0; m < 4; ++m) {
#pragma unroll
        for (int r = 0; r < 4; ++r) {
            int rloc = wr + m * 16 + lg * 4 + r;
            int l = qt * 128 + rloc;
            float isc = iscale[(size_t)bnh * NCL + l];
            float all = fmaxf(isc, csv);
            float c1 = 1.f / all;
            float c2 = (csv / all) * idecay[h * NCL + l];
            const u16* ir = iraw + ((size_t)bnh * NCL + l) * NDK;
            float lsum = 0.f, lsq = 0.f;
#pragma unroll
            for (int n = 0; n < 4; ++n) {
                int col = wc + n * 16 + lr;
                float v = bf2f(ir[col]) * c1 + acc[m][n][r] * c2;
                acc[m][n][r] = v;
                lsum += v; lsq += v * v;
            }
            lsum += __shfl_xor(lsum, 1); lsum += __shfl_xor(lsum, 2);
            lsum += __shfl_xor(lsum, 4); lsum += __shfl_xor(lsum, 8);
            lsq  += __shfl_xor(lsq, 1);  lsq  += __shfl_xor(lsq, 2);
            lsq  += __shfl_xor(lsq, 4);  lsq  += __shfl_xor(lsq, 8);
            if (lr == 0) { atomicAdd(&ssum[rloc], lsum); atomicAdd(&ssq[rloc], lsq); }
        }
    }
    __syncthreads();
#pragma unroll
    for (int m = 0; m < 4; ++m) {
#pragma unroll
        for (int r = 0; r < 4; ++r) {
            int rloc = wr + m * 16 + lg * 4 + r;
            int l = qt * 128 + rloc;
            float mu = ssum[rloc] * (1.f / 128.f);
            float var = ssq[rloc] * (1.f / 128.f) - mu * mu;
            float rstd = rsqrtf(fmaxf(var, 0.f) + 1e-6f);
            int t = cn * NCL + l;
            size_t obase = ((size_t)(b * NT + t)) * ND + (size_t)h * NDK;
#pragma unroll
            for (int n = 0; n < 4; ++n) {
                int col = wc + n * 16 + lr;
                float gv = bf2f(glin[obase + col]);
                float sg = gv / (1.f + expf(-gv));
                float ov = (acc[m][n][r] - mu) * rstd * sg;
                y[obase + col] = f2bf(ov);
            }
        }
    }
}

// ---------------------------------------------------------------------------
extern "C" void kernel_launch(void* const* d_in, const int* in_sizes, int n_in,
                              void* d_out, int out_size, void* d_ws, size_t ws_size,
                              hipStream_t stream)
{
    const float* x    = (const float*)d_in[0];
    const float* sinp = (const float*)d_in[1];
    const float* cosp = (const float*)d_in[2];
    const float* mask = (const float*)d_in[3];
    const float* cdec = (const float*)d_in[4];
    const float* idec = (const float*)d_in[5];
    const float* wq   = (const float*)d_in[6];
    const float* bq   = (const float*)d_in[7];
    const float* wk   = (const float*)d_in[8];
    const float* bk   = (const float*)d_in[9];
    const float* wv   = (const float*)d_in[10];
    const float* bv   = (const float*)d_in[11];
    const float* wg   = (const float*)d_in[12];
    const float* bg   = (const float*)d_in[13];
    const float* wo   = (const float*)d_in[14];
    const float* bo   = (const float*)d_in[15];
    float* out = (float*)d_out;

    // Workspace layout (~248 MB), lifetime-based aliasing (round-8 proven).
    char* ws = (char*)d_ws;
    u16*   XB   = (u16*)(ws + 0);
    u16*   WB   = (u16*)(ws + 33554432);
    u16*   WOB  = (u16*)(ws + 67108864);
    u16*   QR   = (u16*)(ws + 75497472);
    u16*   KR   = (u16*)(ws + 109051904);
    u16*   KRWT = (u16*)(ws + 142606336);
    u16*   VT   = (u16*)(ws + 176160768);
    u16*   GLIN = (u16*)(ws + 209715200);
    float* KVI  = (float*)(ws + 243269632);
    float* CSC  = (float*)(ws + 260046848);
    u16*   IRAW = (u16*)(ws + 0);             // alias XB (dead after gemm1), bf16
    u16*   Y    = KR;                         // alias KR (dead after inner)
    u16*   KVRT = KRWT;                       // alias KRWT (dead after kv)
    float* ISC  = (float*)(ws + 243269632);   // alias KVI (dead after scan)

    k_f2bf_all<<<7168, 256, 0, stream>>>(x, XB,
                                         wq, WB,
                                         wk, WB + 4194304,
                                         wv, WB + 8388608,
                                         wg, WB + 12582912,
                                         wo, WOB);

    k_gemm1<<<1024, 512, 0, stream>>>(XB, WB, bq, bk, bv, bg, sinp, cosp, mask,
                                      QR, KR, KRWT, VT, GLIN);
    k_kv<<<256, 256, 0, stream>>>(KRWT, VT, KVI);
    k_scan<<<32, 256, 0, stream>>>(KVI, cdec, KVRT, CSC);
    k_inner<<<dim3(4, 256), 256, 0, stream>>>(QR, KR, VT, mask, IRAW, ISC);
    k_combine<<<dim3(4, 256), 256, 0, stream>>>(QR, KVRT, IRAW, ISC, CSC, idec, GLIN, Y);
    k_gemm2<<<256, 512, 0, stream>>>(Y, WOB, bo, out);
}

// Round 17
// 813.824 us; speedup vs baseline: 1.0778x; 1.0778x over previous
//
#include <hip/hip_runtime.h>
#include <hip/hip_bf16.h>
#include <math.h>

// Problem constants
#define NB   2
#define NT   4096
#define ND   2048
#define NH   16
#define NDK  128
#define NCL  512
#define NNC  8
#define NTOK 8192
#define SCALING 0.08838834764831845f  // 128^-0.5

typedef unsigned short u16;
typedef short short8 __attribute__((ext_vector_type(8)));
typedef unsigned short ushort8 __attribute__((ext_vector_type(8)));
typedef float f32x4 __attribute__((ext_vector_type(4)));
typedef float float4v __attribute__((ext_vector_type(4)));
typedef short short4v __attribute__((ext_vector_type(4)));

__device__ __forceinline__ float bf2f(u16 u) {
    union { unsigned int i; float f; } v; v.i = ((unsigned int)u) << 16; return v.f;
}
__device__ __forceinline__ u16 f2bf(float f) {
    union { float f; unsigned int i; } v; v.f = f;
    unsigned int r = v.i + 0x7FFFu + ((v.i >> 16) & 1u);
    return (u16)(r >> 16);
}

// async global->LDS, 16B per lane. LDS dest linear: wave base + lane*16.
__device__ __forceinline__ void gload16(const void* g, void* l) {
    __builtin_amdgcn_global_load_lds(
        (const __attribute__((address_space(1))) unsigned int*)g,
        (__attribute__((address_space(3))) unsigned int*)l, 16, 0, 0);
}

#define MFMA16(acc_, a_, b_) acc_ = __builtin_amdgcn_mfma_f32_16x16x32_bf16(a_, b_, acc_, 0, 0, 0)
#define SBAR  asm volatile("s_barrier" ::: "memory")

// ===========================================================================
// ROUND-8 GEMM core (best measured: gemm1 453us): 256x256 tile, barrier-
// minimal (1 sync per K-tile), global_load_lds into non-read buffer pair.
// ===========================================================================

// stage one 128x64 half-tile
__device__ __forceinline__ void stage_half(const u16* __restrict__ g, int ld,
                                           u16* lds, int tid)
{
#pragma unroll
    for (int j = 0; j < 2; ++j) {
        int c = tid + j * 512;            // 0..1023 16B chunks
        int row = c >> 3, u = c & 7;
        gload16(g + (size_t)row * ld + ((u ^ (row & 7)) * 8), lds + (size_t)c * 8);
    }
}

__device__ __forceinline__ void tile_nb(
    int G, int nkt,
    const u16* Aop, const u16* Bop, int ld,
    int tid, int arow, int brow, int uc0, int uc1,
    u16* ARd, u16* BRd, u16* AWr, u16* BWr,
    f32x4 acc[8][4])
{
    if (G + 1 < nkt) {
        const u16* Ag = Aop + (size_t)(G + 1) * 64;
        const u16* Bg = Bop + (size_t)(G + 1) * 64;
        stage_half(Ag,                    ld, AWr,        tid);
        stage_half(Ag + (size_t)128 * ld, ld, AWr + 8192, tid);
        stage_half(Bg,                    ld, BWr,        tid);
        stage_half(Bg + (size_t)128 * ld, ld, BWr + 8192, tid);
    }

    short8 a[4][2], bA[2][2], bB[2][2];

    // group 0: (m0, n0)
#pragma unroll
    for (int mf = 0; mf < 4; ++mf) {
        a[mf][0] = *(const short8*)(ARd + (size_t)(arow + mf * 16) * 64 + uc0);
        a[mf][1] = *(const short8*)(ARd + (size_t)(arow + mf * 16) * 64 + uc1);
    }
#pragma unroll
    for (int nf = 0; nf < 2; ++nf) {
        bA[nf][0] = *(const short8*)(BRd + (size_t)(brow + nf * 16) * 64 + uc0);
        bA[nf][1] = *(const short8*)(BRd + (size_t)(brow + nf * 16) * 64 + uc1);
    }
    __builtin_amdgcn_s_setprio(1);
#pragma unroll
    for (int mf = 0; mf < 4; ++mf)
#pragma unroll
        for (int nf = 0; nf < 2; ++nf) {
            MFMA16(acc[mf][nf], a[mf][0], bA[nf][0]);
            MFMA16(acc[mf][nf], a[mf][1], bA[nf][1]);
        }
    __builtin_amdgcn_s_setprio(0);

    // group 1: (m0, n1)
#pragma unroll
    for (int nf = 0; nf < 2; ++nf) {
        bB[nf][0] = *(const short8*)(BRd + (size_t)(brow + 32 + nf * 16) * 64 + uc0);
        bB[nf][1] = *(const short8*)(BRd + (size_t)(brow + 32 + nf * 16) * 64 + uc1);
    }
    __builtin_amdgcn_s_setprio(1);
#pragma unroll
    for (int mf = 0; mf < 4; ++mf)
#pragma unroll
        for (int nf = 0; nf < 2; ++nf) {
            MFMA16(acc[mf][2 + nf], a[mf][0], bB[nf][0]);
            MFMA16(acc[mf][2 + nf], a[mf][1], bB[nf][1]);
        }
    __builtin_amdgcn_s_setprio(0);

    // group 2: (m1, n1)
#pragma unroll
    for (int mf = 0; mf < 4; ++mf) {
        a[mf][0] = *(const short8*)(ARd + (size_t)(arow + 64 + mf * 16) * 64 + uc0);
        a[mf][1] = *(const short8*)(ARd + (size_t)(arow + 64 + mf * 16) * 64 + uc1);
    }
    __builtin_amdgcn_s_setprio(1);
#pragma unroll
    for (int mf = 0; mf < 4; ++mf)
#pragma unroll
        for (int nf = 0; nf < 2; ++nf) {
            MFMA16(acc[4 + mf][2 + nf], a[mf][0], bB[nf][0]);
            MFMA16(acc[4 + mf][2 + nf], a[mf][1], bB[nf][1]);
        }
    __builtin_amdgcn_s_setprio(0);

    // group 3: (m1, n0)
    __builtin_amdgcn_s_setprio(1);
#pragma unroll
    for (int mf = 0; mf < 4; ++mf)
#pragma unroll
        for (int nf = 0; nf < 2; ++nf) {
            MFMA16(acc[4 + mf][nf], a[mf][0], bA[nf][0]);
            MFMA16(acc[4 + mf][nf], a[mf][1], bA[nf][1]);
        }
    __builtin_amdgcn_s_setprio(0);

    asm volatile("s_waitcnt vmcnt(0) lgkmcnt(0)" ::: "memory");
    SBAR;
}

__device__ __forceinline__ void gemm256_core(
    const u16* Aop, const u16* Bop,
    int ld, int nkt,
    u16* A0, u16* A1, u16* B0, u16* B1, f32x4 acc[8][4])
{
    const int tid  = threadIdx.x;
    const int lane = tid & 63;
    const int lr   = lane & 15;
    const int lg   = lane >> 4;
    const int wid  = tid >> 6;
    const int wm   = wid >> 2;
    const int wn   = wid & 3;

    const int swz  = lr & 7;
    const int uc0  = ((0 * 4 + lg) ^ swz) * 8;
    const int uc1  = ((1 * 4 + lg) ^ swz) * 8;
    const int arow = wm * 128 + lr;
    const int brow = wn * 64 + lr;

    stage_half(Aop,                    ld, A0,        tid);
    stage_half(Aop + (size_t)128 * ld, ld, A0 + 8192, tid);
    stage_half(Bop,                    ld, B0,        tid);
    stage_half(Bop + (size_t)128 * ld, ld, B0 + 8192, tid);
    asm volatile("s_waitcnt vmcnt(0)" ::: "memory");
    SBAR;

    for (int G = 0; G < nkt; G += 2) {
        tile_nb(G,     nkt, Aop, Bop, ld, tid, arow, brow, uc0, uc1,
                A0, B0, A1, B1, acc);
        tile_nb(G + 1, nkt, Aop, Bop, ld, tid, arow, brow, uc0, uc1,
                A1, B1, A0, B0, acc);
    }
}

// ---------------------------------------------------------------------------
// Old 128x128 core (kept for the small GEMMs: kv, combine)
// ---------------------------------------------------------------------------
__device__ __forceinline__ void gemm_bt_core(
    const u16* __restrict__ A, const u16* __restrict__ Bm,
    int lda, int ldb, int K, u16* As, u16* Bs, f32x4 acc[4][4])
{
    const int tid  = threadIdx.x;
    const int lane = tid & 63;
    const int lr   = lane & 15;
    const int lg   = lane >> 4;
    const int wid  = tid >> 6;
    const int wr   = (wid >> 1) * 64;
    const int wc   = (wid & 1) * 64;
    for (int kt = 0; kt < K; kt += 64) {
#pragma unroll
        for (int i = 0; i < 4; ++i) {
            int c = tid + i * 256;
            int row = c >> 3, col = (c & 7) * 8;
            gload16(A  + (size_t)row * lda + kt + col, (char*)As + (size_t)c * 16);
            gload16(Bm + (size_t)row * ldb + kt + col, (char*)Bs + (size_t)c * 16);
        }
        __syncthreads();
#pragma unroll
        for (int kk = 0; kk < 2; ++kk) {
            short8 a[4], b[4];
#pragma unroll
            for (int m = 0; m < 4; ++m)
                a[m] = *(const short8*)(As + (wr + m * 16 + lr) * 64 + kk * 32 + lg * 8);
#pragma unroll
            for (int n = 0; n < 4; ++n)
                b[n] = *(const short8*)(Bs + (wc + n * 16 + lr) * 64 + kk * 32 + lg * 8);
#pragma unroll
            for (int m = 0; m < 4; ++m)
#pragma unroll
                for (int n = 0; n < 4; ++n)
                    acc[m][n] = __builtin_amdgcn_mfma_f32_16x16x32_bf16(a[m], b[n], acc[m][n], 0, 0, 0);
        }
        __syncthreads();
    }
}

// ---------------------------------------------------------------------------
// Merged fp32 -> bf16 convert for all six tensors (one launch).
// ---------------------------------------------------------------------------
__global__ __launch_bounds__(256) void k_f2bf_all(
    const float* __restrict__ sx,  u16* __restrict__ dx,
    const float* __restrict__ s1,  u16* __restrict__ d1,
    const float* __restrict__ s2,  u16* __restrict__ d2,
    const float* __restrict__ s3,  u16* __restrict__ d3,
    const float* __restrict__ s4,  u16* __restrict__ d4,
    const float* __restrict__ s5,  u16* __restrict__ d5)
{
    const float* src;
    u16* dst;
    int n4, base = blockIdx.x;
    if (base < 2048)      { src = sx; dst = dx; n4 = 4194304; }
    else if (base < 3072) { src = s1; dst = d1; n4 = 1048576; base -= 2048; }
    else if (base < 4096) { src = s2; dst = d2; n4 = 1048576; base -= 3072; }
    else if (base < 5120) { src = s3; dst = d3; n4 = 1048576; base -= 4096; }
    else if (base < 6144) { src = s4; dst = d4; n4 = 1048576; base -= 5120; }
    else                  { src = s5; dst = d5; n4 = 1048576; base -= 6144; }
    int nblk = (blockIdx.x < 2048) ? 2048 : 1024;
    int i = base * blockDim.x + threadIdx.x;
    int stride = nblk * blockDim.x;
    for (int j = i; j < n4; j += stride) {
        float4v f = *(const float4v*)(src + (size_t)j * 4);
        short4v o;
        o.x = (short)f2bf(f.x); o.y = (short)f2bf(f.y);
        o.z = (short)f2bf(f.z); o.w = (short)f2bf(f.w);
        *(short4v*)(dst + (size_t)j * 4) = o;
    }
}

// ---------------------------------------------------------------------------
// GEMM1 (round-8 swizzle): [8192 x 2048] x [8192 x 2048]^T; fused epilogue.
// ---------------------------------------------------------------------------
__global__ __launch_bounds__(512, 2) void k_gemm1(
    const u16* __restrict__ xb, const u16* __restrict__ wb,
    const float* __restrict__ bq, const float* __restrict__ bk,
    const float* __restrict__ bv, const float* __restrict__ bg,
    const float* __restrict__ sinp, const float* __restrict__ cosp,
    const float* __restrict__ maskp,
    u16* __restrict__ qro, u16* __restrict__ kro, u16* __restrict__ krwT,
    u16* __restrict__ vT, u16* __restrict__ glin)
{
    __shared__ __align__(16) u16 A0[256 * 64];
    __shared__ __align__(16) u16 A1[256 * 64];
    __shared__ __align__(16) u16 B0[256 * 64];
    __shared__ __align__(16) u16 B1[256 * 64];
    f32x4 acc[8][4];
#pragma unroll
    for (int m = 0; m < 8; ++m)
#pragma unroll
        for (int n = 0; n < 4; ++n) acc[m][n] = (f32x4){0.f, 0.f, 0.f, 0.f};

    int bid = blockIdx.x;
    int swzb = (bid & 7) * 128 + (bid >> 3);
    int mt = swzb >> 5, nt = swzb & 31;

    gemm256_core(xb + (size_t)mt * 256 * ND, wb + (size_t)nt * 256 * ND,
                 ND, ND / 64, A0, A1, B0, B1, acc);

    int tid = threadIdx.x, lane = tid & 63, lr = lane & 15, lg = lane >> 4, wid = tid >> 6;
    int wm = wid >> 2, wn = wid & 3;
    int which = nt >> 3;

    if (which <= 1) {
        const float* bias = (which == 0) ? bq : bk;
#pragma unroll
        for (int mf = 0; mf < 8; ++mf) {
#pragma unroll
            for (int nf = 0; nf < 4; ++nf) {
#pragma unroll
                for (int r = 0; r < 4; ++r) {
                    int row = mt * 256 + wm * 128 + mf * 16 + lg * 4 + r;
                    int col = nt * 256 + wn * 64 + nf * 16 + lr;
                    int f = col & 2047, h = f >> 7, d = f & 127;
                    int b = row >> 12, t = row & 4095, cn = t >> 9, cl = t & 511;
                    float v = acc[mf][nf][r] + bias[f];
                    if (which == 1) v *= SCALING;
                    float sv = sinp[(size_t)t * NDK + d];
                    float cv = cosp[(size_t)t * NDK + d];
                    float vp = __shfl_xor(v, 1);
                    float rot = (lr & 1) ? vp : -vp;
                    float o = v * cv + rot * sv;
                    size_t chbase = (size_t)(b * NNC + cn) * NH + h;
                    if (which == 0) {
                        qro[(chbase * NCL + cl) * NDK + d] = f2bf(o);
                    } else {
                        kro[(chbase * NCL + cl) * NDK + d] = f2bf(o);
                        float w = maskp[((size_t)h * NCL + (NCL - 1)) * NCL + cl];
                        krwT[(chbase * NDK + d) * NCL + cl] = f2bf(o * w);
                    }
                }
            }
        }
    } else {
#pragma unroll
        for (int mf = 0; mf < 8; ++mf) {
#pragma unroll
            for (int nf = 0; nf < 4; ++nf) {
#pragma unroll
                for (int r = 0; r < 4; ++r) {
                    int row = mt * 256 + wm * 128 + mf * 16 + lg * 4 + r;
                    int col = nt * 256 + wn * 64 + nf * 16 + lr;
                    int f = col & 2047;
                    float v = acc[mf][nf][r];
                    if (which == 2) {
                        int h = f >> 7, d = f & 127;
                        int b = row >> 12, t = row & 4095, cn = t >> 9, cl = t & 511;
                        vT[(((size_t)(b * NNC + cn) * NH + h) * NDK + d) * NCL + cl] = f2bf(v + bv[f]);
                    } else {
                        glin[(size_t)row * ND + f] = f2bf(v + bg[f]);
                    }
                }
            }
        }
    }
}

// ---------------------------------------------------------------------------
// GEMM2 (round-8 swizzle): y[8192x2048] x wo[2048x2048]^T + bo -> fp32 out
// ---------------------------------------------------------------------------
__global__ __launch_bounds__(512, 2) void k_gemm2(
    const u16* __restrict__ y, const u16* __restrict__ wob,
    const float* __restrict__ bo, float* __restrict__ out)
{
    __shared__ __align__(16) u16 A0[256 * 64];
    __shared__ __align__(16) u16 A1[256 * 64];
    __shared__ __align__(16) u16 B0[256 * 64];
    __shared__ __align__(16) u16 B1[256 * 64];
    f32x4 acc[8][4];
#pragma unroll
    for (int m = 0; m < 8; ++m)
#pragma unroll
        for (int n = 0; n < 4; ++n) acc[m][n] = (f32x4){0.f, 0.f, 0.f, 0.f};

    int bid = blockIdx.x;
    int swzb = (bid & 7) * 32 + (bid >> 3);
    int mt = swzb >> 3, nt = swzb & 7;

    gemm256_core(y + (size_t)mt * 256 * ND, wob + (size_t)nt * 256 * ND,
                 ND, ND / 64, A0, A1, B0, B1, acc);

    int tid = threadIdx.x, lane = tid & 63, lr = lane & 15, lg = lane >> 4, wid = tid >> 6;
    int wm = wid >> 2, wn = wid & 3;
#pragma unroll
    for (int mf = 0; mf < 8; ++mf)
#pragma unroll
        for (int nf = 0; nf < 4; ++nf)
#pragma unroll
            for (int r = 0; r < 4; ++r) {
                int row = mt * 256 + wm * 128 + mf * 16 + lg * 4 + r;
                int col = nt * 256 + wn * 64 + nf * 16 + lr;
                out[(size_t)row * ND + col] = acc[mf][nf][r] + bo[col];
            }
}

// ---------------------------------------------------------------------------
// Inner retention, KVBLK=64, Q direct-to-reg; iraw stored BF16.
// ---------------------------------------------------------------------------
__global__ __launch_bounds__(256) void k_inner(
    const u16* __restrict__ qr, const u16* __restrict__ kr,
    const u16* __restrict__ vT, const float* __restrict__ mask,
    u16* __restrict__ iraw, float* __restrict__ iscale)
{
    __shared__ __align__(16) u16 Ks[64 * 128];
    __shared__ __align__(16) u16 Vs[128 * 64];
    __shared__ __align__(16) u16 Ps[4][32 * 64];
    __shared__ float sl[128];

    int qt = blockIdx.x, bnh = blockIdx.y;
    int h = bnh & 15;
    const u16* Q = qr + (size_t)bnh * NCL * NDK + (size_t)qt * 128 * NDK;
    const u16* K = kr + (size_t)bnh * NCL * NDK;
    const u16* V = vT + (size_t)bnh * NDK * NCL;
    const float* M = mask + (size_t)h * NCL * NCL + (size_t)qt * 128 * NCL;

    int tid = threadIdx.x, lane = tid & 63, lr = lane & 15, lg = lane >> 4, wid = tid >> 6;
    if (tid < 128) sl[tid] = 0.f;

    short8 aq[2][4];
#pragma unroll
    for (int i = 0; i < 2; ++i)
#pragma unroll
        for (int kk = 0; kk < 4; ++kk)
            aq[i][kk] = *(const short8*)(Q + (size_t)(wid * 32 + i * 16 + lr) * NDK + kk * 32 + lg * 8);

    f32x4 acc[2][8];
#pragma unroll
    for (int i = 0; i < 2; ++i)
#pragma unroll
        for (int n = 0; n < 8; ++n) acc[i][n] = (f32x4){0.f, 0.f, 0.f, 0.f};

    int msteps = qt * 2 + 2;
    for (int ms = 0; ms < msteps; ++ms) {
        int mb = ms * 64;
#pragma unroll
        for (int i = 0; i < 4; ++i) {
            int c = tid + i * 256;
            int row = c >> 4, cc = (c & 15) * 8;
            gload16(K + (size_t)(mb + row) * NDK + cc, (char*)Ks + (size_t)c * 16);
        }
#pragma unroll
        for (int i = 0; i < 4; ++i) {
            int c = tid + i * 256;
            int row = c >> 3, cc = (c & 7) * 8;
            gload16(V + (size_t)row * NCL + mb + cc, (char*)Vs + (size_t)c * 16);
        }
        __syncthreads();

        f32x4 pa[2][4];
#pragma unroll
        for (int i = 0; i < 2; ++i)
#pragma unroll
            for (int nf = 0; nf < 4; ++nf) pa[i][nf] = (f32x4){0.f, 0.f, 0.f, 0.f};
#pragma unroll
        for (int kk = 0; kk < 4; ++kk) {
#pragma unroll
            for (int nf = 0; nf < 4; ++nf) {
                short8 bk = *(const short8*)(Ks + (size_t)(nf * 16 + lr) * 128 + kk * 32 + lg * 8);
#pragma unroll
                for (int i = 0; i < 2; ++i)
                    pa[i][nf] = __builtin_amdgcn_mfma_f32_16x16x32_bf16(aq[i][kk], bk, pa[i][nf], 0, 0, 0);
            }
        }
#pragma unroll
        for (int i = 0; i < 2; ++i) {
#pragma unroll
            for (int r = 0; r < 4; ++r) {
                int rloc = i * 16 + lg * 4 + r;
                int row128 = wid * 32 + rloc;
                float ss = 0.f;
#pragma unroll
                for (int nf = 0; nf < 4; ++nf) {
                    float mv = M[(size_t)row128 * NCL + mb + nf * 16 + lr];
                    float p = pa[i][nf][r] * mv;
                    ss += fabsf(p);
                    Ps[wid][rloc * 64 + nf * 16 + lr] = f2bf(p);
                }
                ss += __shfl_xor(ss, 1); ss += __shfl_xor(ss, 2);
                ss += __shfl_xor(ss, 4); ss += __shfl_xor(ss, 8);
                if (lr == 0) sl[row128] += ss;
            }
        }
        __syncthreads();

        short8 ap[2][2];
#pragma unroll
        for (int i = 0; i < 2; ++i)
#pragma unroll
            for (int ks = 0; ks < 2; ++ks)
                ap[i][ks] = *(const short8*)(Ps[wid] + (i * 16 + lr) * 64 + ks * 32 + lg * 8);
#pragma unroll
        for (int n = 0; n < 8; ++n) {
#pragma unroll
            for (int ks = 0; ks < 2; ++ks) {
                short8 bv8 = *(const short8*)(Vs + (size_t)(n * 16 + lr) * 64 + ks * 32 + lg * 8);
#pragma unroll
                for (int i = 0; i < 2; ++i)
                    acc[i][n] = __builtin_amdgcn_mfma_f32_16x16x32_bf16(ap[i][ks], bv8, acc[i][n], 0, 0, 0);
            }
        }
        __syncthreads();
    }

    u16* OR = iraw + ((size_t)bnh * NCL + (size_t)qt * 128) * NDK;
#pragma unroll
    for (int i = 0; i < 2; ++i)
#pragma unroll
        for (int n = 0; n < 8; ++n)
#pragma unroll
            for (int r = 0; r < 4; ++r) {
                int row = wid * 32 + i * 16 + lg * 4 + r;
                int col = n * 16 + lr;
                OR[(size_t)row * NDK + col] = f2bf(acc[i][n][r]);
            }
    if (tid < 128) iscale[(size_t)bnh * NCL + qt * 128 + tid] = fmaxf(1.f, sl[tid]);
}

// ---------------------------------------------------------------------------
// kv_i[k][d] = sum_l krw[l][k] * v[l][d]
// ---------------------------------------------------------------------------
__global__ __launch_bounds__(256) void k_kv(
    const u16* __restrict__ krwT, const u16* __restrict__ vT, float* __restrict__ kvi)
{
    __shared__ __align__(16) u16 As[128 * 64];
    __shared__ __align__(16) u16 Bs[128 * 64];
    f32x4 acc[4][4];
#pragma unroll
    for (int m = 0; m < 4; ++m)
#pragma unroll
        for (int n = 0; n < 4; ++n) acc[m][n] = (f32x4){0.f, 0.f, 0.f, 0.f};

    int bnh = blockIdx.x;
    gemm_bt_core(krwT + (size_t)bnh * NDK * NCL, vT + (size_t)bnh * NDK * NCL,
                 NCL, NCL, NCL, As, Bs, acc);

    int tid = threadIdx.x, lane = tid & 63, lr = lane & 15, lg = lane >> 4, wid = tid >> 6;
    int wr = (wid >> 1) * 64, wc = (wid & 1) * 64;
    float* O = kvi + (size_t)bnh * NDK * NDK;
#pragma unroll
    for (int m = 0; m < 4; ++m)
#pragma unroll
        for (int n = 0; n < 4; ++n)
#pragma unroll
            for (int r = 0; r < 4; ++r) {
                int row = wr + m * 16 + lg * 4 + r;
                int col = wc + n * 16 + lr;
                O[(size_t)row * NDK + col] = acc[m][n][r];
            }
}

// ---------------------------------------------------------------------------
// Recurrent scan over chunks
// ---------------------------------------------------------------------------
__global__ __launch_bounds__(256) void k_scan(
    const float* __restrict__ kvi, const float* __restrict__ cdec,
    u16* __restrict__ kvrT, float* __restrict__ csc)
{
    int bh = blockIdx.x;
    int b = bh >> 4, h = bh & 15;
    float cd = cdec[h];
    int tid = threadIdx.x;
    int col = tid & 127;
    int r0 = (tid >> 7) * 64;
    float st[64];
#pragma unroll
    for (int i = 0; i < 64; ++i) st[i] = 0.f;
    float scale = 1.f;
    __shared__ float cs[128];
    __shared__ float scsh;

    for (int n = 0; n < NNC; ++n) {
        size_t idx = (size_t)((b * NNC + n) * NH + h);
        size_t kb = idx * (NDK * NDK);
        float inv = 1.f / scale;
#pragma unroll
        for (int i = 0; i < 64; ++i)
            kvrT[kb + (size_t)col * NDK + r0 + i] = f2bf(st[i] * inv);
        if (tid == 0) csc[idx] = scale;

        const float* KV = kvi + kb;
        float colsum = 0.f;
#pragma unroll
        for (int i = 0; i < 64; ++i) {
            float xv = st[i] * cd + KV[(size_t)(r0 + i) * NDK + col];
            st[i] = xv;
            colsum += fabsf(xv);
        }
        __syncthreads();
        if (tid < 128) cs[tid] = 0.f;
        __syncthreads();
        atomicAdd(&cs[col], colsum);
        __syncthreads();
        if (tid == 0) {
            float mx = cs[0];
            for (int i = 1; i < 128; ++i) mx = fmaxf(mx, cs[i]);
            scsh = fmaxf(1.f, mx);
        }
        __syncthreads();
        scale = scsh;
    }
}

// ---------------------------------------------------------------------------
// Combine (iraw read as BF16)
// ---------------------------------------------------------------------------
__global__ __launch_bounds__(256) void k_combine(
    const u16* __restrict__ qr, const u16* __restrict__ kvrT,
    const u16* __restrict__ iraw, const float* __restrict__ iscale,
    const float* __restrict__ cscale, const float* __restrict__ idecay,
    const u16* __restrict__ glin, u16* __restrict__ y)
{
    __shared__ __align__(16) u16 As[128 * 64];
    __shared__ __align__(16) u16 Bs[128 * 64];
    __shared__ float ssum[128];
    __shared__ float ssq[128];
    f32x4 acc[4][4];
#pragma unroll
    for (int m = 0; m < 4; ++m)
#pragma unroll
        for (int n = 0; n < 4; ++n) acc[m][n] = (f32x4){0.f, 0.f, 0.f, 0.f};

    int qt = blockIdx.x, bnh = blockIdx.y;
    int b = bnh >> 7, cn = (bnh >> 4) & 7, h = bnh & 15;
    gemm_bt_core(qr + (size_t)bnh * NCL * NDK + (size_t)qt * 128 * NDK,
                 kvrT + (size_t)bnh * NDK * NDK, NDK, NDK, NDK, As, Bs, acc);

    int tid = threadIdx.x, lane = tid & 63, lr = lane & 15, lg = lane >> 4, wid = tid >> 6;
    int wr = (wid >> 1) * 64, wc = (wid & 1) * 64;
    if (tid < 128) { ssum[tid] = 0.f; ssq[tid] = 0.f; }
    __syncthreads();
    float csv = cscale[bnh];

#pragma unroll
    for (int m = 0; m < 4; ++m) {
#pragma unroll
        for (int r = 0; r < 4; ++r) {
            int rloc = wr + m * 16 + lg * 4 + r;
            int l = qt * 128 + rloc;
            float isc = iscale[(size_t)bnh * NCL + l];
            float all = fmaxf(isc, csv);
            float c1 = 1.f / all;
            float c2 = (csv / all) * idecay[h * NCL + l];
            const u16* ir = iraw + ((size_t)bnh * NCL + l) * NDK;
            float lsum = 0.f, lsq = 0.f;
#pragma unroll
            for (int n = 0; n < 4; ++n) {
                int col = wc + n * 16 + lr;
                float v = bf2f(ir[col]) * c1 + acc[m][n][r] * c2;
                acc[m][n][r] = v;
                lsum += v; lsq += v * v;
            }
            lsum += __shfl_xor(lsum, 1); lsum += __shfl_xor(lsum, 2);
            lsum += __shfl_xor(lsum, 4); lsum += __shfl_xor(lsum, 8);
            lsq  += __shfl_xor(lsq, 1);  lsq  += __shfl_xor(lsq, 2);
            lsq  += __shfl_xor(lsq, 4);  lsq  += __shfl_xor(lsq, 8);
            if (lr == 0) { atomicAdd(&ssum[rloc], lsum); atomicAdd(&ssq[rloc], lsq); }
        }
    }
    __syncthreads();
#pragma unroll
    for (int m = 0; m < 4; ++m) {
#pragma unroll
        for (int r = 0; r < 4; ++r) {
            int rloc = wr + m * 16 + lg * 4 + r;
            int l = qt * 128 + rloc;
            float mu = ssum[rloc] * (1.f / 128.f);
            float var = ssq[rloc] * (1.f / 128.f) - mu * mu;
            float rstd = rsqrtf(fmaxf(var, 0.f) + 1e-6f);
            int t = cn * NCL + l;
            size_t obase = ((size_t)(b * NT + t)) * ND + (size_t)h * NDK;
#pragma unroll
            for (int n = 0; n < 4; ++n) {
                int col = wc + n * 16 + lr;
                float gv = bf2f(glin[obase + col]);
                float sg = gv / (1.f + expf(-gv));
                float ov = (acc[m][n][r] - mu) * rstd * sg;
                y[obase + col] = f2bf(ov);
            }
        }
    }
}

// ---------------------------------------------------------------------------
extern "C" void kernel_launch(void* const* d_in, const int* in_sizes, int n_in,
                              void* d_out, int out_size, void* d_ws, size_t ws_size,
                              hipStream_t stream)
{
    const float* x    = (const float*)d_in[0];
    const float* sinp = (const float*)d_in[1];
    const float* cosp = (const float*)d_in[2];
    const float* mask = (const float*)d_in[3];
    const float* cdec = (const float*)d_in[4];
    const float* idec = (const float*)d_in[5];
    const float* wq   = (const float*)d_in[6];
    const float* bq   = (const float*)d_in[7];
    const float* wk   = (const float*)d_in[8];
    const float* bk   = (const float*)d_in[9];
    const float* wv   = (const float*)d_in[10];
    const float* bv   = (const float*)d_in[11];
    const float* wg   = (const float*)d_in[12];
    const float* bg   = (const float*)d_in[13];
    const float* wo   = (const float*)d_in[14];
    const float* bo   = (const float*)d_in[15];
    float* out = (float*)d_out;

    // Workspace layout (~248 MB), lifetime-based aliasing (round-8 proven).
    char* ws = (char*)d_ws;
    u16*   XB   = (u16*)(ws + 0);
    u16*   WB   = (u16*)(ws + 33554432);
    u16*   WOB  = (u16*)(ws + 67108864);
    u16*   QR   = (u16*)(ws + 75497472);
    u16*   KR   = (u16*)(ws + 109051904);
    u16*   KRWT = (u16*)(ws + 142606336);
    u16*   VT   = (u16*)(ws + 176160768);
    u16*   GLIN = (u16*)(ws + 209715200);
    float* KVI  = (float*)(ws + 243269632);
    float* CSC  = (float*)(ws + 260046848);
    u16*   IRAW = (u16*)(ws + 0);             // alias XB (dead after gemm1), bf16
    u16*   Y    = KR;                         // alias KR (dead after inner)
    u16*   KVRT = KRWT;                       // alias KRWT (dead after kv)
    float* ISC  = (float*)(ws + 243269632);   // alias KVI (dead after scan)

    k_f2bf_all<<<7168, 256, 0, stream>>>(x, XB,
                                         wq, WB,
                                         wk, WB + 4194304,
                                         wv, WB + 8388608,
                                         wg, WB + 12582912,
                                         wo, WOB);

    k_gemm1<<<1024, 512, 0, stream>>>(XB, WB, bq, bk, bv, bg, sinp, cosp, mask,
                                      QR, KR, KRWT, VT, GLIN);
    k_kv<<<256, 256, 0, stream>>>(KRWT, VT, KVI);
    k_scan<<<32, 256, 0, stream>>>(KVI, cdec, KVRT, CSC);
    k_inner<<<dim3(4, 256), 256, 0, stream>>>(QR, KR, VT, mask, IRAW, ISC);
    k_combine<<<dim3(4, 256), 256, 0, stream>>>(QR, KVRT, IRAW, ISC, CSC, idec, GLIN, Y);
    k_gemm2<<<256, 512, 0, stream>>>(Y, WOB, bo, out);
}